// Round 4
// baseline (1060.339 us; speedup 1.0000x reference)
//
#include <hip/hip_runtime.h>
#include <hip/hip_bf16.h>
#include <math.h>

#define N_NODES 50000
#define N_EDGES 800000
#define DIM 128
#define NH 4

typedef __attribute__((ext_vector_type(8))) short bf16x8;
typedef __attribute__((ext_vector_type(4))) float f32x4;
typedef unsigned int uint;
typedef unsigned short ushort;

__device__ inline short f2bf(float f) {
  __hip_bfloat16 h = __float2bfloat16(f);
  return __builtin_bit_cast(short, h);
}
__device__ inline uint pack_bf2(float lo, float hi) {
  return (uint)(ushort)f2bf(lo) | ((uint)(ushort)f2bf(hi) << 16);
}

// ---------------- BN stats: per-column sum & sumsq ----------------
__global__ __launch_bounds__(256) void bn_stats_kernel(
    const float* __restrict__ x, int M, float* __restrict__ out /*[sum128, sq128]*/) {
  __shared__ float s_sum[DIM];
  __shared__ float s_sq[DIM];
  int t = threadIdx.x;  // 256
  if (t < DIM) { s_sum[t] = 0.f; s_sq[t] = 0.f; }
  __syncthreads();
  int c4 = (t & 31) * 4;
  int rg = t >> 5;
  float sum0=0,sum1=0,sum2=0,sum3=0, sq0=0,sq1=0,sq2=0,sq3=0;
  for (long row = (long)blockIdx.x * 8 + rg; row < M; row += (long)gridDim.x * 8) {
    float4 v = *reinterpret_cast<const float4*>(x + row * DIM + c4);
    sum0 += v.x; sq0 += v.x * v.x;
    sum1 += v.y; sq1 += v.y * v.y;
    sum2 += v.z; sq2 += v.z * v.z;
    sum3 += v.w; sq3 += v.w * v.w;
  }
  atomicAdd(&s_sum[c4 + 0], sum0); atomicAdd(&s_sq[c4 + 0], sq0);
  atomicAdd(&s_sum[c4 + 1], sum1); atomicAdd(&s_sq[c4 + 1], sq1);
  atomicAdd(&s_sum[c4 + 2], sum2); atomicAdd(&s_sq[c4 + 2], sq2);
  atomicAdd(&s_sum[c4 + 3], sum3); atomicAdd(&s_sq[c4 + 3], sq3);
  __syncthreads();
  if (t < DIM) {
    atomicAdd(&out[t], s_sum[t]);
    atomicAdd(&out[DIM + t], s_sq[t]);
  }
}

// ---------------- finalize affine a,b from stats (node + edge fused) ----------------
__global__ __launch_bounds__(128) void finalize2_kernel(
    const float* __restrict__ stats_n, const float* __restrict__ stats_e,
    const float* __restrict__ g1n, const float* __restrict__ b1n,
    const float* __restrict__ g1e, const float* __restrict__ b1e,
    float* __restrict__ ab_n, float* __restrict__ ab_e) {
  int t = threadIdx.x;
  const float* stats = blockIdx.x ? stats_e : stats_n;
  const float* gamma = blockIdx.x ? g1e : g1n;
  const float* beta  = blockIdx.x ? b1e : b1n;
  float* ab          = blockIdx.x ? ab_e : ab_n;
  float M            = blockIdx.x ? (float)N_EDGES : (float)N_NODES;
  float mean = stats[t] / M;
  float var = stats[DIM + t] / M - mean * mean;
  float a = gamma[t] * rsqrtf(var + 1e-5f);
  ab[t] = a;
  ab[DIM + t] = beta[t] - mean * a;
}

// ---------------- finalize affine for BN2 ----------------
__global__ __launch_bounds__(128) void finalize_ab_kernel(
    const float* __restrict__ stats, float M,
    const float* __restrict__ gamma, const float* __restrict__ beta,
    float* __restrict__ ab) {
  int t = threadIdx.x;
  float mean = stats[t] / M;
  float var = stats[DIM + t] / M - mean * mean;
  float a = gamma[t] * rsqrtf(var + 1e-5f);
  ab[t] = a;
  ab[DIM + t] = beta[t] - mean * a;
}

// ---- fold BN affine (+scale) into all 4 weights, PERMUTED columns, bf16 T ----
// phys col d -> logical col L = (ct>>1)*32 + lr*2 + (ct&1),  ct=d>>4, lr=d&15.
// WT[d][k] = bf16(scale * a[k] * W[k][L]);  bias[d] = scale * sum_k b[k]*W[k][L]
__global__ __launch_bounds__(1024) void fold4_kernel(
    const float* __restrict__ Wq, const float* __restrict__ Wk,
    const float* __restrict__ Wv, const float* __restrict__ We,
    const float* __restrict__ ab_n, const float* __restrict__ ab_e, float inv_s,
    short* __restrict__ WqT, short* __restrict__ WkT,
    short* __restrict__ WvT, short* __restrict__ WeT,
    float* __restrict__ bq, float* __restrict__ bk,
    float* __restrict__ bv, float* __restrict__ be) {
  __shared__ float red[8][DIM];
  int b = blockIdx.x;
  const float* W = (b == 0) ? Wq : (b == 1) ? Wk : (b == 2) ? Wv : We;
  const float* ab = (b == 3) ? ab_e : ab_n;
  float scale = (b == 1) ? inv_s : 1.f;
  short* WT = (b == 0) ? WqT : (b == 1) ? WkT : (b == 2) ? WvT : WeT;
  float* bias = (b == 0) ? bq : (b == 1) ? bk : (b == 2) ? bv : be;
  int t = threadIdx.x;
  int d = t & 127, kg = t >> 7;
  int ct = d >> 4, lr = d & 15;
  int L = (ct >> 1) * 32 + lr * 2 + (ct & 1);
  float bacc = 0.f;
#pragma unroll
  for (int j = 0; j < 16; ++j) {
    int k = kg * 16 + j;
    float wv = W[k * DIM + L];
    WT[d * DIM + k] = f2bf(scale * ab[k] * wv);
    bacc += ab[DIM + k] * wv;
  }
  red[kg][d] = bacc;
  __syncthreads();
  if (kg == 0) {
    float s = 0.f;
#pragma unroll
    for (int j = 0; j < 8; ++j) s += red[j][d];
    bias[d] = scale * s;
  }
}

// ---- load A fragments (4 k-steps) for 16 rows starting at m0, fp32->bf16 ----
__device__ inline void load_a_frags(const float* __restrict__ X, long m0,
                                    int lr, int lg, bf16x8 a[4]) {
#pragma unroll
  for (int ks = 0; ks < 4; ++ks) {
    const float* p = X + (m0 + lr) * DIM + ks * 32 + lg * 8;
    float4 v0 = *reinterpret_cast<const float4*>(p);
    float4 v1 = *reinterpret_cast<const float4*>(p + 4);
    bf16x8 af;
    af[0] = f2bf(v0.x); af[1] = f2bf(v0.y); af[2] = f2bf(v0.z); af[3] = f2bf(v0.w);
    af[4] = f2bf(v1.x); af[5] = f2bf(v1.y); af[6] = f2bf(v1.z); af[7] = f2bf(v1.w);
    a[ks] = af;
  }
}

// ---------------- QKV via MFMA -> packed bf16 (natural logical layout) ----------------
__global__ __launch_bounds__(256) void qkv_mfma_kernel(
    const float* __restrict__ nf,
    const short* __restrict__ WqT, const short* __restrict__ WkT, const short* __restrict__ WvT,
    const float* __restrict__ bq, const float* __restrict__ bk, const float* __restrict__ bv,
    ushort* __restrict__ Qb, ushort* __restrict__ Kb, ushort* __restrict__ Vb) {
  int t = threadIdx.x;
  int w = t >> 6, l = t & 63;
  int lr = l & 15, lg = l >> 4;
  long m0 = (long)blockIdx.x * 64 + w * 16;
  if (m0 >= N_NODES) return;  // tail waves
  bf16x8 a[4];
  load_a_frags(nf, m0, lr, lg, a);
  const short* Ws[3] = {WqT, WkT, WvT};
  const float* bs[3] = {bq, bk, bv};
  ushort* Os[3] = {Qb, Kb, Vb};
#pragma unroll 1
  for (int m = 0; m < 3; ++m) {
    const short* WT = Ws[m];
    f32x4 acc[8];
#pragma unroll
    for (int ct = 0; ct < 8; ++ct) acc[ct] = (f32x4){0.f, 0.f, 0.f, 0.f};
#pragma unroll
    for (int ct = 0; ct < 8; ++ct) {
#pragma unroll
      for (int ks = 0; ks < 4; ++ks) {
        bf16x8 b = *reinterpret_cast<const bf16x8*>(WT + (ct * 16 + lr) * DIM + ks * 32 + lg * 8);
        acc[ct] = __builtin_amdgcn_mfma_f32_16x16x32_bf16(a[ks], b, acc[ct], 0, 0, 0);
      }
    }
    const float* bb = bs[m];
    ushort* O = Os[m];
#pragma unroll
    for (int h = 0; h < 4; ++h) {
      float b0 = bb[(2 * h) * 16 + lr];
      float b1 = bb[(2 * h + 1) * 16 + lr];
#pragma unroll
      for (int r = 0; r < 4; ++r) {
        uint u = pack_bf2(acc[2 * h][r] + b0, acc[2 * h + 1][r] + b1);
        *reinterpret_cast<uint*>(O + (m0 + lg * 4 + r) * DIM + h * 32 + lr * 2) = u;
      }
    }
  }
}

// ---------------- CSR build ----------------
__global__ __launch_bounds__(256) void hist_kernel(
    const int* __restrict__ dst, int* __restrict__ deg) {
  int i = blockIdx.x * 256 + threadIdx.x;
  atomicAdd(&deg[dst[i]], 1);
}

#define SCAN_T 1024
#define PER_T 49
__global__ __launch_bounds__(SCAN_T) void scan_kernel(
    const int* __restrict__ deg, int* __restrict__ row_start, int* __restrict__ cursor) {
  __shared__ int ps[SCAN_T];
  int t = threadIdx.x;
  int base = t * PER_T;
  int lsum = 0;
  int local[PER_T];
#pragma unroll
  for (int j = 0; j < PER_T; ++j) {
    int idx = base + j;
    int d = (idx < N_NODES) ? deg[idx] : 0;
    local[j] = lsum;
    lsum += d;
  }
  ps[t] = lsum;
  __syncthreads();
  for (int off = 1; off < SCAN_T; off <<= 1) {
    int v = (t >= off) ? ps[t - off] : 0;
    __syncthreads();
    ps[t] += v;
    __syncthreads();
  }
  int prefix = (t == 0) ? 0 : ps[t - 1];
#pragma unroll
  for (int j = 0; j < PER_T; ++j) {
    int idx = base + j;
    if (idx < N_NODES) {
      int v = prefix + local[j];
      row_start[idx] = v;
      cursor[idx] = v;
    }
  }
  if (t == SCAN_T - 1) row_start[N_NODES] = ps[SCAN_T - 1];
}

__global__ __launch_bounds__(256) void scatter_kernel(
    const int* __restrict__ src, const int* __restrict__ dst,
    int* __restrict__ cursor, int2* __restrict__ csr) {
  int i = blockIdx.x * 256 + threadIdx.x;
  int d = dst[i];
  int pos = atomicAdd(&cursor[d], 1);
  csr[pos] = make_int2(src[i], i);
}

// ------- edge score: MFMA proj (permuted) + packed bf16 K/Q gathers -------
__global__ __launch_bounds__(256) void edge_score_kernel(
    const float* __restrict__ ef,
    const int* __restrict__ src, const int* __restrict__ dst,
    const short* __restrict__ WeT, const float* __restrict__ be,
    const ushort* __restrict__ Qb, const ushort* __restrict__ Kb,
    float* __restrict__ s_out) {
  int t = threadIdx.x;
  int w = t >> 6, l = t & 63;
  int lr = l & 15, lg = l >> 4;
  long m0 = (long)blockIdx.x * 64 + w * 16;
  long eb = m0 + lg * 4;

  // src/dst for this lane-group's 4 edges (uniform across the 16 lr lanes)
  int4 s4 = *reinterpret_cast<const int4*>(src + eb);
  int4 d4 = *reinterpret_cast<const int4*>(dst + eb);
  int sn[4] = {s4.x, s4.y, s4.z, s4.w};
  int dn[4] = {d4.x, d4.y, d4.z, d4.w};

  // prefetch packed K/Q pairs: lane lr covers logical cols {h*32+lr*2, +1}
  uint Kg[4][4], Qg[4][4];
#pragma unroll
  for (int r = 0; r < 4; ++r) {
#pragma unroll
    for (int h = 0; h < 4; ++h) {
      Kg[r][h] = *reinterpret_cast<const uint*>(Kb + (long)sn[r] * DIM + h * 32 + lr * 2);
      Qg[r][h] = *reinterpret_cast<const uint*>(Qb + (long)dn[r] * DIM + h * 32 + lr * 2);
    }
  }

  bf16x8 a[4];
  load_a_frags(ef, m0, lr, lg, a);
  float ber[8];
#pragma unroll
  for (int ct = 0; ct < 8; ++ct) ber[ct] = be[ct * 16 + lr];

  f32x4 acc[8];
#pragma unroll
  for (int ct = 0; ct < 8; ++ct) acc[ct] = (f32x4){0.f, 0.f, 0.f, 0.f};
#pragma unroll
  for (int ct = 0; ct < 8; ++ct) {
#pragma unroll
    for (int ks = 0; ks < 4; ++ks) {
      bf16x8 b = *reinterpret_cast<const bf16x8*>(WeT + (ct * 16 + lr) * DIM + ks * 32 + lg * 8);
      acc[ct] = __builtin_amdgcn_mfma_f32_16x16x32_bf16(a[ks], b, acc[ct], 0, 0, 0);
    }
  }

  // acc[ct][r] + ber[ct] = pe at logical col (ct>>1)*32 + lr*2 + (ct&1); head = ct>>1
#pragma unroll
  for (int r = 0; r < 4; ++r) {
    float hs0, hs1, hs2, hs3;
    {
      float h0, h1, h2, h3;
#pragma unroll
      for (int h = 0; h < 4; ++h) {
        float k0 = __builtin_bit_cast(float, Kg[r][h] << 16);
        float k1 = __builtin_bit_cast(float, Kg[r][h] & 0xffff0000u);
        float q0 = __builtin_bit_cast(float, Qg[r][h] << 16);
        float q1 = __builtin_bit_cast(float, Qg[r][h] & 0xffff0000u);
        float pe0 = acc[2 * h][r] + ber[2 * h];
        float pe1 = acc[2 * h + 1][r] + ber[2 * h + 1];
        float v = fminf(fmaxf(k0 * q0, -5.f), 5.f) * pe0
                + fminf(fmaxf(k1 * q1, -5.f), 5.f) * pe1;
        if (h == 0) h0 = v; else if (h == 1) h1 = v; else if (h == 2) h2 = v; else h3 = v;
      }
      hs0 = h0; hs1 = h1; hs2 = h2; hs3 = h3;
    }
#pragma unroll
    for (int m2 = 8; m2 >= 1; m2 >>= 1) {
      hs0 += __shfl_xor(hs0, m2);
      hs1 += __shfl_xor(hs1, m2);
      hs2 += __shfl_xor(hs2, m2);
      hs3 += __shfl_xor(hs3, m2);
    }
    if (lr < 4) {
      float myh = (lr == 0) ? hs0 : ((lr == 1) ? hs1 : ((lr == 2) ? hs2 : hs3));
      s_out[(eb + r) * 4 + lr] = __expf(fminf(fmaxf(myh, -5.f), 5.f));
    }
  }
}

// ------- aggregate: one wave per dst node over its CSR row; V packed bf16 -------
__global__ __launch_bounds__(256) void aggregate_kernel(
    const int* __restrict__ row_start, const int2* __restrict__ csr,
    const float* __restrict__ s_arr, const ushort* __restrict__ Vb,
    float* __restrict__ hagg) {
  int t = threadIdx.x;
  int w = t >> 6, l = t & 63;
  int n = blockIdx.x * 4 + w;
  int r0 = row_start[n], r1 = row_start[n + 1];
  int h = l >> 4;
  float a0 = 0.f, a1 = 0.f, zacc = 0.f;
  for (int idx = r0; idx < r1; ++idx) {
    int2 rec = csr[idx];
    float sh = s_arr[(long)rec.y * 4 + h];
    uint u = *reinterpret_cast<const uint*>(Vb + (long)rec.x * DIM + l * 2);
    float v0 = __builtin_bit_cast(float, u << 16);
    float v1 = __builtin_bit_cast(float, u & 0xffff0000u);
    a0 += sh * v0; a1 += sh * v1; zacc += sh;
  }
  float inv = 1.f / (zacc + 1e-6f);
  float2 o; o.x = a0 * inv; o.y = a1 * inv;
  *reinterpret_cast<float2*>(hagg + (long)n * DIM + l * 2) = o;
}

// ---------------- attention out (256 thr): h = hagg @ O_w + O_b + res; BN2 stats ----------------
__global__ __launch_bounds__(256) void attnout_kernel(
    const float* __restrict__ hagg,
    const float* __restrict__ Ow, const float* __restrict__ Ob,
    const float* __restrict__ h_in1,
    float* __restrict__ hres, float* __restrict__ stats2) {
  __shared__ float rows[16][DIM];
  int t = threadIdx.x;
  int c = t & 127, half = t >> 7;
  int n0 = blockIdx.x * 16;
  for (int i = half; i < 16; i += 2) rows[i][c] = hagg[(long)(n0 + i) * DIM + c];
  __syncthreads();
  float acc[8];
  float ob = Ob[c];
#pragma unroll
  for (int i = 0; i < 8; ++i) acc[i] = ob;
  for (int c4 = 0; c4 < 32; ++c4) {
    float w0 = Ow[(4 * c4 + 0) * DIM + c];
    float w1 = Ow[(4 * c4 + 1) * DIM + c];
    float w2 = Ow[(4 * c4 + 2) * DIM + c];
    float w3 = Ow[(4 * c4 + 3) * DIM + c];
#pragma unroll
    for (int i = 0; i < 8; ++i) {
      float4 r = *reinterpret_cast<const float4*>(&rows[half * 8 + i][4 * c4]);
      acc[i] += r.x * w0 + r.y * w1 + r.z * w2 + r.w * w3;
    }
  }
  float lsum = 0.f, lsq = 0.f;
#pragma unroll
  for (int i = 0; i < 8; ++i) {
    long idx = (long)(n0 + half * 8 + i) * DIM + c;
    float hv = h_in1[idx] + acc[i];
    hres[idx] = hv;
    lsum += hv; lsq += hv * hv;
  }
  atomicAdd(&stats2[c], lsum);
  atomicAdd(&stats2[DIM + c], lsq);
}

// ---------------- MLP: 8 nodes per block, 256 threads ----------------
__global__ __launch_bounds__(256) void mlp_kernel(
    const float* hres, const float* __restrict__ ab2,
    const float* __restrict__ W1, const float* __restrict__ W2,
    float* out) {
  __shared__ float rows[8][DIM];
  __shared__ float mid[8][2 * DIM];
  int t = threadIdx.x;
  int n0 = blockIdx.x * 8;
  {
    int c = t & 127;
    int half = t >> 7;
    float a = ab2[c], b = ab2[DIM + c];
    for (int i = half; i < 8; i += 2) {
      float hv = hres[(long)(n0 + i) * DIM + c];
      rows[i][c] = a * hv + b;
    }
  }
  __syncthreads();
  float acc[8];
#pragma unroll
  for (int i = 0; i < 8; ++i) acc[i] = 0.f;
  for (int c4 = 0; c4 < 32; ++c4) {
    float w0 = W1[(4 * c4 + 0) * 2 * DIM + t];
    float w1 = W1[(4 * c4 + 1) * 2 * DIM + t];
    float w2 = W1[(4 * c4 + 2) * 2 * DIM + t];
    float w3 = W1[(4 * c4 + 3) * 2 * DIM + t];
#pragma unroll
    for (int i = 0; i < 8; ++i) {
      float4 r = *reinterpret_cast<const float4*>(&rows[i][4 * c4]);
      acc[i] += r.x * w0 + r.y * w1 + r.z * w2 + r.w * w3;
    }
  }
#pragma unroll
  for (int i = 0; i < 8; ++i) {
    float x = acc[i];
    mid[i][t] = x / (1.f + __expf(-x));
  }
  __syncthreads();
  int d = t & 127;
  int half = t >> 7;
  float acc2[4];
#pragma unroll
  for (int j = 0; j < 4; ++j) acc2[j] = 0.f;
  for (int k4 = 0; k4 < 64; ++k4) {
    float w0 = W2[(4 * k4 + 0) * DIM + d];
    float w1 = W2[(4 * k4 + 1) * DIM + d];
    float w2 = W2[(4 * k4 + 2) * DIM + d];
    float w3 = W2[(4 * k4 + 3) * DIM + d];
#pragma unroll
    for (int j = 0; j < 4; ++j) {
      float4 mv = *reinterpret_cast<const float4*>(&mid[half + j * 2][4 * k4]);
      acc2[j] += mv.x * w0 + mv.y * w1 + mv.z * w2 + mv.w * w3;
    }
  }
#pragma unroll
  for (int j = 0; j < 4; ++j) {
    int i = half + j * 2;
    long idx = (long)(n0 + i) * DIM + d;
    out[idx] = hres[idx] + acc2[j];
  }
}

extern "C" void kernel_launch(void* const* d_in, const int* in_sizes, int n_in,
                              void* d_out, int out_size, void* d_ws, size_t ws_size,
                              hipStream_t stream) {
  const float* node_feats = (const float*)d_in[0];
  const float* edge_feats = (const float*)d_in[1];
  const int* src = (const int*)d_in[2];
  const int* dst = (const int*)d_in[3];
  const float* Wq = (const float*)d_in[4];
  const float* Wk = (const float*)d_in[5];
  const float* Wv = (const float*)d_in[6];
  const float* We = (const float*)d_in[7];
  const float* Ow = (const float*)d_in[8];
  const float* Ob = (const float*)d_in[9];
  const float* g1n = (const float*)d_in[10];
  const float* b1n = (const float*)d_in[11];
  const float* g1e = (const float*)d_in[12];
  const float* b1e = (const float*)d_in[13];
  const float* g2 = (const float*)d_in[14];
  const float* b2 = (const float*)d_in[15];
  const float* W1 = (const float*)d_in[16];
  const float* W2 = (const float*)d_in[17];
  float* out = (float*)d_out;
  float* w = (float*)d_ws;

  float* stats_n = w + 0;
  float* stats_e = w + 256;
  float* stats_h = w + 512;
  float* ab_n = w + 768;
  float* ab_e = w + 1024;
  float* ab_2 = w + 1280;
  float* bq = w + 1536;
  float* bk = w + 1664;
  float* bv = w + 1792;
  float* be = w + 1920;
  short* WqT = (short*)(w + 2048);
  short* WkT = (short*)(w + 10240);
  short* WvT = (short*)(w + 18432);
  short* WeT = (short*)(w + 26624);
  ushort* Qb = (ushort*)(w + 34816);                 // N*128 bf16 = 3.2M floats
  ushort* Kb = (ushort*)(w + 3234816);
  ushort* Vb = (ushort*)(w + 6434816);
  float* s_arr = w + 9634816;                        // E*4 floats
  int* deg = (int*)(w + 12834816);
  int* row_start = deg + 50048;
  int* cursor = row_start + 50064;
  int2* csr = (int2*)(cursor + 50048);               // 8B-aligned (even float offset)
  float* hagg = w + 34816;                           // overlays Qb+Kb (dead after edge_score)

  const float inv_s = 0.17677669529663687f;  // 1/sqrt(32), folded into K

  hipMemsetAsync(w, 0, 768 * sizeof(float), stream);
  hipMemsetAsync(deg, 0, 50000 * sizeof(int), stream);

  bn_stats_kernel<<<512, 256, 0, stream>>>(node_feats, N_NODES, stats_n);
  bn_stats_kernel<<<2048, 256, 0, stream>>>(edge_feats, N_EDGES, stats_e);
  finalize2_kernel<<<2, 128, 0, stream>>>(stats_n, stats_e, g1n, b1n, g1e, b1e, ab_n, ab_e);
  fold4_kernel<<<4, 1024, 0, stream>>>(Wq, Wk, Wv, We, ab_n, ab_e, inv_s,
                                       WqT, WkT, WvT, WeT, bq, bk, bv, be);

  hist_kernel<<<N_EDGES / 256, 256, 0, stream>>>(dst, deg);
  scan_kernel<<<1, SCAN_T, 0, stream>>>(deg, row_start, cursor);
  scatter_kernel<<<N_EDGES / 256, 256, 0, stream>>>(src, dst, cursor, csr);

  qkv_mfma_kernel<<<(N_NODES + 63) / 64, 256, 0, stream>>>(
      node_feats, WqT, WkT, WvT, bq, bk, bv, Qb, Kb, Vb);
  edge_score_kernel<<<N_EDGES / 64, 256, 0, stream>>>(
      edge_feats, src, dst, WeT, be, Qb, Kb, s_arr);
  aggregate_kernel<<<N_NODES / 4, 256, 0, stream>>>(row_start, csr, s_arr, Vb, hagg);
  attnout_kernel<<<N_NODES / 16, 256, 0, stream>>>(hagg, Ow, Ob, node_feats, out, stats_h);
  finalize_ab_kernel<<<1, 128, 0, stream>>>(stats_h, (float)N_NODES, g2, b2, ab_2);
  mlp_kernel<<<N_NODES / 8, 256, 0, stream>>>(out, ab_2, W1, W2, out);
}

// Round 7
// 808.864 us; speedup vs baseline: 1.3109x; 1.3109x over previous
//
#include <hip/hip_runtime.h>
#include <hip/hip_bf16.h>
#include <math.h>

#define N_NODES 50000
#define N_EDGES 800000
#define DIM 128
#define NH 4

typedef __attribute__((ext_vector_type(8))) short bf16x8;
typedef __attribute__((ext_vector_type(4))) float f32x4;
typedef unsigned int uint;
typedef unsigned short ushort;

__device__ inline short f2bf(float f) {
  __hip_bfloat16 h = __float2bfloat16(f);
  return __builtin_bit_cast(short, h);
}
__device__ inline uint pack_bf2(float lo, float hi) {
  return (uint)(ushort)f2bf(lo) | ((uint)(ushort)f2bf(hi) << 16);
}
__device__ inline float bflo(uint u) { return __builtin_bit_cast(float, u << 16); }
__device__ inline float bfhi(uint u) { return __builtin_bit_cast(float, u & 0xffff0000u); }

// ---------------- BN stats: per-column sum & sumsq ----------------
__global__ __launch_bounds__(256) void bn_stats_kernel(
    const float* __restrict__ x, int M, float* __restrict__ out) {
  __shared__ float s_sum[DIM];
  __shared__ float s_sq[DIM];
  int t = threadIdx.x;
  if (t < DIM) { s_sum[t] = 0.f; s_sq[t] = 0.f; }
  __syncthreads();
  int c4 = (t & 31) * 4;
  int rg = t >> 5;
  float sum0=0,sum1=0,sum2=0,sum3=0, sq0=0,sq1=0,sq2=0,sq3=0;
  for (long row = (long)blockIdx.x * 8 + rg; row < M; row += (long)gridDim.x * 8) {
    float4 v = *reinterpret_cast<const float4*>(x + row * DIM + c4);
    sum0 += v.x; sq0 += v.x * v.x;
    sum1 += v.y; sq1 += v.y * v.y;
    sum2 += v.z; sq2 += v.z * v.z;
    sum3 += v.w; sq3 += v.w * v.w;
  }
  atomicAdd(&s_sum[c4 + 0], sum0); atomicAdd(&s_sq[c4 + 0], sq0);
  atomicAdd(&s_sum[c4 + 1], sum1); atomicAdd(&s_sq[c4 + 1], sq1);
  atomicAdd(&s_sum[c4 + 2], sum2); atomicAdd(&s_sq[c4 + 2], sq2);
  atomicAdd(&s_sum[c4 + 3], sum3); atomicAdd(&s_sq[c4 + 3], sq3);
  __syncthreads();
  if (t < DIM) {
    atomicAdd(&out[t], s_sum[t]);
    atomicAdd(&out[DIM + t], s_sq[t]);
  }
}

// ---------------- finalize affine a,b (node + edge fused) ----------------
__global__ __launch_bounds__(128) void finalize2_kernel(
    const float* __restrict__ stats_n, const float* __restrict__ stats_e,
    const float* __restrict__ g1n, const float* __restrict__ b1n,
    const float* __restrict__ g1e, const float* __restrict__ b1e,
    float* __restrict__ ab_n, float* __restrict__ ab_e) {
  int t = threadIdx.x;
  const float* stats = blockIdx.x ? stats_e : stats_n;
  const float* gamma = blockIdx.x ? g1e : g1n;
  const float* beta  = blockIdx.x ? b1e : b1n;
  float* ab          = blockIdx.x ? ab_e : ab_n;
  float M            = blockIdx.x ? (float)N_EDGES : (float)N_NODES;
  float mean = stats[t] / M;
  float var = stats[DIM + t] / M - mean * mean;
  float a = gamma[t] * rsqrtf(var + 1e-5f);
  ab[t] = a;
  ab[DIM + t] = beta[t] - mean * a;
}

__global__ __launch_bounds__(128) void finalize_ab_kernel(
    const float* __restrict__ stats, float M,
    const float* __restrict__ gamma, const float* __restrict__ beta,
    float* __restrict__ ab) {
  int t = threadIdx.x;
  float mean = stats[t] / M;
  float var = stats[DIM + t] / M - mean * mean;
  float a = gamma[t] * rsqrtf(var + 1e-5f);
  ab[t] = a;
  ab[DIM + t] = beta[t] - mean * a;
}

// ---- fold BN affine (+scale) into Wq/Wk/Wv/We, PERMUTED columns, bf16 T ----
__global__ __launch_bounds__(1024) void fold4_kernel(
    const float* __restrict__ Wq, const float* __restrict__ Wk,
    const float* __restrict__ Wv, const float* __restrict__ We,
    const float* __restrict__ ab_n, const float* __restrict__ ab_e, float inv_s,
    short* __restrict__ WqT, short* __restrict__ WkT,
    short* __restrict__ WvT, short* __restrict__ WeT,
    float* __restrict__ bq, float* __restrict__ bk,
    float* __restrict__ bv, float* __restrict__ be) {
  __shared__ float red[8][DIM];
  int b = blockIdx.x;
  const float* W = (b == 0) ? Wq : (b == 1) ? Wk : (b == 2) ? Wv : We;
  const float* ab = (b == 3) ? ab_e : ab_n;
  float scale = (b == 1) ? inv_s : 1.f;
  short* WT = (b == 0) ? WqT : (b == 1) ? WkT : (b == 2) ? WvT : WeT;
  float* bias = (b == 0) ? bq : (b == 1) ? bk : (b == 2) ? bv : be;
  int t = threadIdx.x;
  int d = t & 127, kg = t >> 7;
  int ct = d >> 4, lr = d & 15;
  int L = (ct >> 1) * 32 + lr * 2 + (ct & 1);
  float bacc = 0.f;
#pragma unroll
  for (int j = 0; j < 16; ++j) {
    int k = kg * 16 + j;
    float wv = W[k * DIM + L];
    WT[d * DIM + k] = f2bf(scale * ab[k] * wv);
    bacc += ab[DIM + k] * wv;
  }
  red[kg][d] = bacc;
  __syncthreads();
  if (kg == 0) {
    float s = 0.f;
#pragma unroll
    for (int j = 0; j < 8; ++j) s += red[j][d];
    bias[d] = scale * s;
  }
}

// ---- transpose-cast Ow and W2 to bf16 (no fold needed) ----
__global__ __launch_bounds__(256) void fold_static_kernel(
    const float* __restrict__ Ow, const float* __restrict__ W2,
    short* __restrict__ OwT, short* __restrict__ W2T) {
  int t = threadIdx.x;
  int d = t & 127, kh = t >> 7;
  if (blockIdx.x == 0) {
    for (int j = 0; j < 64; ++j) {
      int k = kh * 64 + j;
      OwT[d * DIM + k] = f2bf(Ow[k * DIM + d]);
    }
  } else {
    for (int j = 0; j < 128; ++j) {
      int k = kh * 128 + j;
      W2T[d * 256 + k] = f2bf(W2[k * DIM + d]);
    }
  }
}

// ---- fold BN2 affine into W1: W1F[d][k] = ab2a[k]*W1[k][d], bias1[d] = sum ab2b[k]*W1[k][d] ----
__global__ __launch_bounds__(256) void fold_w1_kernel(
    const float* __restrict__ W1, const float* __restrict__ ab2,
    short* __restrict__ W1F, float* __restrict__ bias1) {
  int d = threadIdx.x;  // 256
  float bacc = 0.f;
  for (int k = 0; k < DIM; ++k) {
    float wv = W1[k * 256 + d];
    W1F[d * DIM + k] = f2bf(ab2[k] * wv);
    bacc += ab2[DIM + k] * wv;
  }
  bias1[d] = bacc;
}

// ---- load A fragments (4 k-steps) for 16 rows at m0, fp32->bf16 ----
__device__ inline void load_a_frags(const float* __restrict__ X, long m0,
                                    int lr, int lg, bf16x8 a[4]) {
#pragma unroll
  for (int ks = 0; ks < 4; ++ks) {
    const float* p = X + (m0 + lr) * DIM + ks * 32 + lg * 8;
    float4 v0 = *reinterpret_cast<const float4*>(p);
    float4 v1 = *reinterpret_cast<const float4*>(p + 4);
    bf16x8 af;
    af[0] = f2bf(v0.x); af[1] = f2bf(v0.y); af[2] = f2bf(v0.z); af[3] = f2bf(v0.w);
    af[4] = f2bf(v1.x); af[5] = f2bf(v1.y); af[6] = f2bf(v1.z); af[7] = f2bf(v1.w);
    a[ks] = af;
  }
}

// ---------------- QKV via MFMA -> packed bf16 ----------------
__global__ __launch_bounds__(256) void qkv_mfma_kernel(
    const float* __restrict__ nf,
    const short* __restrict__ WqT, const short* __restrict__ WkT, const short* __restrict__ WvT,
    const float* __restrict__ bq, const float* __restrict__ bk, const float* __restrict__ bv,
    ushort* __restrict__ Qb, ushort* __restrict__ Kb, ushort* __restrict__ Vb) {
  int t = threadIdx.x;
  int w = t >> 6, l = t & 63;
  int lr = l & 15, lg = l >> 4;
  long m0 = (long)blockIdx.x * 64 + w * 16;
  if (m0 >= N_NODES) return;
  bf16x8 a[4];
  load_a_frags(nf, m0, lr, lg, a);
  const short* Ws[3] = {WqT, WkT, WvT};
  const float* bs[3] = {bq, bk, bv};
  ushort* Os[3] = {Qb, Kb, Vb};
#pragma unroll 1
  for (int m = 0; m < 3; ++m) {
    const short* WT = Ws[m];
    f32x4 acc[8];
#pragma unroll
    for (int ct = 0; ct < 8; ++ct) acc[ct] = (f32x4){0.f, 0.f, 0.f, 0.f};
#pragma unroll
    for (int ct = 0; ct < 8; ++ct) {
#pragma unroll
      for (int ks = 0; ks < 4; ++ks) {
        bf16x8 b = *reinterpret_cast<const bf16x8*>(WT + (ct * 16 + lr) * DIM + ks * 32 + lg * 8);
        acc[ct] = __builtin_amdgcn_mfma_f32_16x16x32_bf16(a[ks], b, acc[ct], 0, 0, 0);
      }
    }
    const float* bb = bs[m];
    ushort* O = Os[m];
#pragma unroll
    for (int h = 0; h < 4; ++h) {
      float b0 = bb[(2 * h) * 16 + lr];
      float b1 = bb[(2 * h + 1) * 16 + lr];
#pragma unroll
      for (int r = 0; r < 4; ++r) {
        uint u = pack_bf2(acc[2 * h][r] + b0, acc[2 * h + 1][r] + b1);
        *reinterpret_cast<uint*>(O + (m0 + lg * 4 + r) * DIM + h * 32 + lr * 2) = u;
      }
    }
  }
}

// ---------------- CSR build ----------------
__global__ __launch_bounds__(256) void hist_kernel(
    const int* __restrict__ dst, int* __restrict__ deg) {
  int i = blockIdx.x * 256 + threadIdx.x;
  atomicAdd(&deg[dst[i]], 1);
}

#define SCAN_T 1024
#define PER_T 49
__global__ __launch_bounds__(SCAN_T) void scan_kernel(
    const int* __restrict__ deg, int* __restrict__ row_start, int* __restrict__ cursor) {
  __shared__ int ps[SCAN_T];
  int t = threadIdx.x;
  int base = t * PER_T;
  int lsum = 0;
  int local[PER_T];
#pragma unroll
  for (int j = 0; j < PER_T; ++j) {
    int idx = base + j;
    int d = (idx < N_NODES) ? deg[idx] : 0;
    local[j] = lsum;
    lsum += d;
  }
  ps[t] = lsum;
  __syncthreads();
  for (int off = 1; off < SCAN_T; off <<= 1) {
    int v = (t >= off) ? ps[t - off] : 0;
    __syncthreads();
    ps[t] += v;
    __syncthreads();
  }
  int prefix = (t == 0) ? 0 : ps[t - 1];
#pragma unroll
  for (int j = 0; j < PER_T; ++j) {
    int idx = base + j;
    if (idx < N_NODES) {
      int v = prefix + local[j];
      row_start[idx] = v;
      cursor[idx] = v;
    }
  }
  if (t == SCAN_T - 1) row_start[N_NODES] = ps[SCAN_T - 1];
}

__global__ __launch_bounds__(256) void scatter_kernel(
    const int* __restrict__ src, const int* __restrict__ dst,
    int* __restrict__ cursor, int2* __restrict__ csr) {
  int i = blockIdx.x * 256 + threadIdx.x;
  int d = dst[i];
  int pos = atomicAdd(&cursor[d], 1);
  csr[pos] = make_int2(src[i], i);
}

// ------- edge score: persistent, software-pipelined -------
#define ES_GRID 1024
__global__ __launch_bounds__(256) void edge_score_kernel(
    const float* __restrict__ ef,
    const int* __restrict__ src, const int* __restrict__ dst,
    const short* __restrict__ WeT, const float* __restrict__ be,
    const ushort* __restrict__ Qb, const ushort* __restrict__ Kb,
    float* __restrict__ s_out) {
  const int NT = N_EDGES / 64;
  int t = threadIdx.x;
  int w = t >> 6, l = t & 63;
  int lr = l & 15, lg = l >> 4;
  int stride = gridDim.x;
  float ber[8];
#pragma unroll
  for (int ct = 0; ct < 8; ++ct) ber[ct] = be[ct * 16 + lr];

  int tile = blockIdx.x;
  // prologue: load sd + ef rows for first tile
  int4 s4, d4;
  f32x4 af[8];
  {
    long m0 = (long)tile * 64 + w * 16;
    long eb = m0 + lg * 4;
    s4 = *reinterpret_cast<const int4*>(src + eb);
    d4 = *reinterpret_cast<const int4*>(dst + eb);
#pragma unroll
    for (int ks = 0; ks < 4; ++ks) {
      const float* p = ef + (m0 + lr) * DIM + ks * 32 + lg * 8;
      af[2 * ks]     = __builtin_nontemporal_load(reinterpret_cast<const f32x4*>(p));
      af[2 * ks + 1] = __builtin_nontemporal_load(reinterpret_cast<const f32x4*>(p + 4));
    }
  }

#pragma unroll 2
  for (; tile < NT; tile += stride) {
    int pt = (tile + stride < NT) ? (tile + stride) : (NT - 1);
    // 1. issue K/Q gathers for current tile (sd ready)
    int sn[4] = {s4.x, s4.y, s4.z, s4.w};
    int dn[4] = {d4.x, d4.y, d4.z, d4.w};
    uint Kg[4][4], Qg[4][4];
#pragma unroll
    for (int r = 0; r < 4; ++r) {
#pragma unroll
      for (int h = 0; h < 4; ++h) {
        Kg[r][h] = *reinterpret_cast<const uint*>(Kb + (long)sn[r] * DIM + h * 32 + lr * 2);
        Qg[r][h] = *reinterpret_cast<const uint*>(Qb + (long)dn[r] * DIM + h * 32 + lr * 2);
      }
    }
    // 2. issue next tile's src/dst
    long pm0 = (long)pt * 64 + w * 16;
    long peb = pm0 + lg * 4;
    int4 ns4 = *reinterpret_cast<const int4*>(src + peb);
    int4 nd4 = *reinterpret_cast<const int4*>(dst + peb);
    // 3. convert current ef rows to bf16 frags
    bf16x8 a[4];
#pragma unroll
    for (int ks = 0; ks < 4; ++ks) {
      f32x4 v0 = af[2 * ks], v1 = af[2 * ks + 1];
      bf16x8 t8;
      t8[0] = f2bf(v0.x); t8[1] = f2bf(v0.y); t8[2] = f2bf(v0.z); t8[3] = f2bf(v0.w);
      t8[4] = f2bf(v1.x); t8[5] = f2bf(v1.y); t8[6] = f2bf(v1.z); t8[7] = f2bf(v1.w);
      a[ks] = t8;
    }
    // 4. issue next tile's ef rows
    f32x4 naf[8];
#pragma unroll
    for (int ks = 0; ks < 4; ++ks) {
      const float* p = ef + (pm0 + lr) * DIM + ks * 32 + lg * 8;
      naf[2 * ks]     = __builtin_nontemporal_load(reinterpret_cast<const f32x4*>(p));
      naf[2 * ks + 1] = __builtin_nontemporal_load(reinterpret_cast<const f32x4*>(p + 4));
    }
    // 5. MFMA projection (hides gather latency)
    f32x4 acc[8];
#pragma unroll
    for (int ct = 0; ct < 8; ++ct) acc[ct] = (f32x4){0.f, 0.f, 0.f, 0.f};
#pragma unroll
    for (int ct = 0; ct < 8; ++ct) {
#pragma unroll
      for (int ks = 0; ks < 4; ++ks) {
        bf16x8 b = *reinterpret_cast<const bf16x8*>(WeT + (ct * 16 + lr) * DIM + ks * 32 + lg * 8);
        acc[ct] = __builtin_amdgcn_mfma_f32_16x16x32_bf16(a[ks], b, acc[ct], 0, 0, 0);
      }
    }
    // 6. score + reduce + store
    long eb = (long)tile * 64 + w * 16 + lg * 4;
#pragma unroll
    for (int r = 0; r < 4; ++r) {
      float hs0, hs1, hs2, hs3;
      {
        float h0, h1, h2, h3;
#pragma unroll
        for (int h = 0; h < 4; ++h) {
          float k0 = bflo(Kg[r][h]), k1 = bfhi(Kg[r][h]);
          float q0 = bflo(Qg[r][h]), q1 = bfhi(Qg[r][h]);
          float pe0 = acc[2 * h][r] + ber[2 * h];
          float pe1 = acc[2 * h + 1][r] + ber[2 * h + 1];
          float v = fminf(fmaxf(k0 * q0, -5.f), 5.f) * pe0
                  + fminf(fmaxf(k1 * q1, -5.f), 5.f) * pe1;
          if (h == 0) h0 = v; else if (h == 1) h1 = v; else if (h == 2) h2 = v; else h3 = v;
        }
        hs0 = h0; hs1 = h1; hs2 = h2; hs3 = h3;
      }
#pragma unroll
      for (int m2 = 8; m2 >= 1; m2 >>= 1) {
        hs0 += __shfl_xor(hs0, m2);
        hs1 += __shfl_xor(hs1, m2);
        hs2 += __shfl_xor(hs2, m2);
        hs3 += __shfl_xor(hs3, m2);
      }
      if (lr < 4) {
        float myh = (lr == 0) ? hs0 : ((lr == 1) ? hs1 : ((lr == 2) ? hs2 : hs3));
        s_out[(eb + r) * 4 + lr] = __expf(fminf(fmaxf(myh, -5.f), 5.f));
      }
    }
    // 7. rotate prefetch buffers
    s4 = ns4; d4 = nd4;
#pragma unroll
    for (int i = 0; i < 8; ++i) af[i] = naf[i];
  }
}

// ------- aggregate: one wave per dst node, 2-edge unrolled -------
__global__ __launch_bounds__(256) void aggregate_kernel(
    const int* __restrict__ row_start, const int2* __restrict__ csr,
    const float* __restrict__ s_arr, const ushort* __restrict__ Vb,
    float* __restrict__ hagg) {
  int t = threadIdx.x;
  int w = t >> 6, l = t & 63;
  int n = blockIdx.x * 4 + w;
  int r0 = row_start[n], r1 = row_start[n + 1];
  int h = l >> 4;
  float a0 = 0.f, a1 = 0.f, zacc = 0.f;
  int idx = r0;
  for (; idx + 2 <= r1; idx += 2) {
    int2 ra = csr[idx];
    int2 rb = csr[idx + 1];
    float sa = s_arr[(long)ra.y * 4 + h];
    float sb = s_arr[(long)rb.y * 4 + h];
    uint ua = *reinterpret_cast<const uint*>(Vb + (long)ra.x * DIM + l * 2);
    uint ub = *reinterpret_cast<const uint*>(Vb + (long)rb.x * DIM + l * 2);
    a0 += sa * bflo(ua) + sb * bflo(ub);
    a1 += sa * bfhi(ua) + sb * bfhi(ub);
    zacc += sa + sb;
  }
  if (idx < r1) {
    int2 ra = csr[idx];
    float sa = s_arr[(long)ra.y * 4 + h];
    uint ua = *reinterpret_cast<const uint*>(Vb + (long)ra.x * DIM + l * 2);
    a0 += sa * bflo(ua);
    a1 += sa * bfhi(ua);
    zacc += sa;
  }
  float inv = 1.f / (zacc + 1e-6f);
  float2 o; o.x = a0 * inv; o.y = a1 * inv;
  *reinterpret_cast<float2*>(hagg + (long)n * DIM + l * 2) = o;
}

// ---------------- attnout via MFMA: hres = h_in1 + hagg @ Ow + Ob; BN2 stats ----------------
__global__ __launch_bounds__(256) void attnout_mfma_kernel(
    const float* __restrict__ hagg, const short* __restrict__ OwT,
    const float* __restrict__ Ob, const float* __restrict__ h_in1,
    float* __restrict__ hres, float* __restrict__ stats2) {
  int t = threadIdx.x;
  int w = t >> 6, l = t & 63;
  int lr = l & 15, lg = l >> 4;
  long m0 = (long)blockIdx.x * 64 + w * 16;
  if (m0 >= N_NODES) return;
  bf16x8 a[4];
  load_a_frags(hagg, m0, lr, lg, a);
  f32x4 acc[8];
#pragma unroll
  for (int ct = 0; ct < 8; ++ct) acc[ct] = (f32x4){0.f, 0.f, 0.f, 0.f};
#pragma unroll
  for (int ct = 0; ct < 8; ++ct) {
#pragma unroll
    for (int ks = 0; ks < 4; ++ks) {
      bf16x8 b = *reinterpret_cast<const bf16x8*>(OwT + (ct * 16 + lr) * DIM + ks * 32 + lg * 8);
      acc[ct] = __builtin_amdgcn_mfma_f32_16x16x32_bf16(a[ks], b, acc[ct], 0, 0, 0);
    }
  }
#pragma unroll
  for (int ct = 0; ct < 8; ++ct) {
    float ob = Ob[ct * 16 + lr];
    float ls = 0.f, lq = 0.f;
#pragma unroll
    for (int r = 0; r < 4; ++r) {
      long idx = (m0 + lg * 4 + r) * DIM + ct * 16 + lr;
      float hv = h_in1[idx] + acc[ct][r] + ob;
      hres[idx] = hv;
      ls += hv; lq += hv * hv;
    }
    ls += __shfl_xor(ls, 16); ls += __shfl_xor(ls, 32);
    lq += __shfl_xor(lq, 16); lq += __shfl_xor(lq, 32);
    if (lg == 0) {
      atomicAdd(&stats2[ct * 16 + lr], ls);
      atomicAdd(&stats2[DIM + ct * 16 + lr], lq);
    }
  }
}

// ---------------- MLP via MFMA: out = hres + silu(BN2(hres) @ W1) @ W2 ----------------
__global__ __launch_bounds__(256) void mlp_mfma_kernel(
    const float* __restrict__ hres, const short* __restrict__ W1F,
    const float* __restrict__ bias1, const short* __restrict__ W2T,
    float* __restrict__ out) {
  __shared__ short mid[64][264];  // padded: 2-way bank conflicts only
  int t = threadIdx.x;
  int w = t >> 6, l = t & 63;
  int lr = l & 15, lg = l >> 4;
  long m0 = (long)blockIdx.x * 64 + w * 16;
  if (m0 >= N_NODES) return;
  // layer 1: A = raw hres (BN folded into W1F/bias1)
  bf16x8 a1[4];
  load_a_frags(hres, m0, lr, lg, a1);
#pragma unroll
  for (int ct = 0; ct < 16; ++ct) {
    f32x4 acc = (f32x4){0.f, 0.f, 0.f, 0.f};
#pragma unroll
    for (int ks = 0; ks < 4; ++ks) {
      bf16x8 b = *reinterpret_cast<const bf16x8*>(W1F + (ct * 16 + lr) * DIM + ks * 32 + lg * 8);
      acc = __builtin_amdgcn_mfma_f32_16x16x32_bf16(a1[ks], b, acc, 0, 0, 0);
    }
    float bb = bias1[ct * 16 + lr];
#pragma unroll
    for (int r = 0; r < 4; ++r) {
      float x = acc[r] + bb;
      float sl = x / (1.f + __expf(-x));
      mid[w * 16 + lg * 4 + r][ct * 16 + lr] = f2bf(sl);
    }
  }
  // layer 2: A = mid (own rows; same-wave ds ordering)
  bf16x8 a2[8];
#pragma unroll
  for (int ks = 0; ks < 8; ++ks) {
    a2[ks] = *reinterpret_cast<const bf16x8*>(&mid[w * 16 + lr][ks * 32 + lg * 8]);
  }
#pragma unroll
  for (int ct = 0; ct < 8; ++ct) {
    f32x4 acc = (f32x4){0.f, 0.f, 0.f, 0.f};
#pragma unroll
    for (int ks = 0; ks < 8; ++ks) {
      bf16x8 b = *reinterpret_cast<const bf16x8*>(W2T + (ct * 16 + lr) * 256 + ks * 32 + lg * 8);
      acc = __builtin_amdgcn_mfma_f32_16x16x32_bf16(a2[ks], b, acc, 0, 0, 0);
    }
#pragma unroll
    for (int r = 0; r < 4; ++r) {
      long idx = (m0 + lg * 4 + r) * DIM + ct * 16 + lr;
      out[idx] = hres[idx] + acc[r];
    }
  }
}

extern "C" void kernel_launch(void* const* d_in, const int* in_sizes, int n_in,
                              void* d_out, int out_size, void* d_ws, size_t ws_size,
                              hipStream_t stream) {
  const float* node_feats = (const float*)d_in[0];
  const float* edge_feats = (const float*)d_in[1];
  const int* src = (const int*)d_in[2];
  const int* dst = (const int*)d_in[3];
  const float* Wq = (const float*)d_in[4];
  const float* Wk = (const float*)d_in[5];
  const float* Wv = (const float*)d_in[6];
  const float* We = (const float*)d_in[7];
  const float* Ow = (const float*)d_in[8];
  const float* Ob = (const float*)d_in[9];
  const float* g1n = (const float*)d_in[10];
  const float* b1n = (const float*)d_in[11];
  const float* g1e = (const float*)d_in[12];
  const float* b1e = (const float*)d_in[13];
  const float* g2 = (const float*)d_in[14];
  const float* b2 = (const float*)d_in[15];
  const float* W1 = (const float*)d_in[16];
  const float* W2 = (const float*)d_in[17];
  float* out = (float*)d_out;
  float* w = (float*)d_ws;

  float* stats_n = w + 0;
  float* stats_e = w + 256;
  float* stats_h = w + 512;
  float* ab_n = w + 768;
  float* ab_e = w + 1024;
  float* ab_2 = w + 1280;
  float* bq = w + 1536;
  float* bk = w + 1664;
  float* bv = w + 1792;
  float* be = w + 1920;
  short* WqT = (short*)(w + 2048);    // 128x128 bf16 = 8192 floats
  short* WkT = (short*)(w + 10240);
  short* WvT = (short*)(w + 18432);
  short* WeT = (short*)(w + 26624);
  short* OwT = (short*)(w + 34816);   // 128x128 bf16 = 8192 floats
  short* W1F = (short*)(w + 43008);   // 256x128 bf16 = 16384 floats  (FIXED size)
  short* W2T = (short*)(w + 59392);   // 128x256 bf16 = 16384 floats  (FIXED size)
  float* bias1 = w + 75776;           // 256
  ushort* Qb = (ushort*)(w + 76032);  // N*128 bf16 = 3.2M floats
  ushort* Kb = (ushort*)(w + 3276032);
  ushort* Vb = (ushort*)(w + 6476032);
  float* s_arr = w + 9676032;         // E*4 floats
  int* deg = (int*)(w + 12876032);
  int* row_start = deg + 50048;
  int* cursor = row_start + 50064;
  int2* csr = (int2*)(cursor + 50048);
  float* hagg = w + 76032;            // overlays Qb+Kb (dead after edge_score); ends at Vb

  const float inv_s = 0.17677669529663687f;  // 1/sqrt(32), folded into K

  hipMemsetAsync(w, 0, 768 * sizeof(float), stream);
  hipMemsetAsync(deg, 0, 50000 * sizeof(int), stream);

  bn_stats_kernel<<<512, 256, 0, stream>>>(node_feats, N_NODES, stats_n);
  bn_stats_kernel<<<2048, 256, 0, stream>>>(edge_feats, N_EDGES, stats_e);
  finalize2_kernel<<<2, 128, 0, stream>>>(stats_n, stats_e, g1n, b1n, g1e, b1e, ab_n, ab_e);
  fold4_kernel<<<4, 1024, 0, stream>>>(Wq, Wk, Wv, We, ab_n, ab_e, inv_s,
                                       WqT, WkT, WvT, WeT, bq, bk, bv, be);
  fold_static_kernel<<<2, 256, 0, stream>>>(Ow, W2, OwT, W2T);

  hist_kernel<<<N_EDGES / 256, 256, 0, stream>>>(dst, deg);
  scan_kernel<<<1, SCAN_T, 0, stream>>>(deg, row_start, cursor);
  scatter_kernel<<<N_EDGES / 256, 256, 0, stream>>>(src, dst, cursor, csr);

  qkv_mfma_kernel<<<(N_NODES + 63) / 64, 256, 0, stream>>>(
      node_feats, WqT, WkT, WvT, bq, bk, bv, Qb, Kb, Vb);
  edge_score_kernel<<<ES_GRID, 256, 0, stream>>>(
      edge_feats, src, dst, WeT, be, Qb, Kb, s_arr);
  aggregate_kernel<<<N_NODES / 4, 256, 0, stream>>>(row_start, csr, s_arr, Vb, hagg);
  attnout_mfma_kernel<<<(N_NODES + 63) / 64, 256, 0, stream>>>(
      hagg, OwT, Ob, node_feats, out, stats_h);
  finalize_ab_kernel<<<1, 128, 0, stream>>>(stats_h, (float)N_NODES, g2, b2, ab_2);
  fold_w1_kernel<<<1, 256, 0, stream>>>(W1, ab_2, W1F, bias1);
  mlp_mfma_kernel<<<(N_NODES + 63) / 64, 256, 0, stream>>>(out, W1F, bias1, W2T, out);
}